// Round 7
// baseline (169.334 us; speedup 1.0000x reference)
//
#include <hip/hip_runtime.h>

#define BIG 1e10f
#define H 256
#define W 256
#define NPIX (H * W)
// images: 0..7 = pred batch, 8..15 = target batch
// ws layout:
//   [0, 16384)            double partial[2048]   (one per row_pass block)
//   [16384, 16448)        int flags[16]          (fg.any() per image)
//   [32768, 32768+8MB)    float2 g2[16][H][W]    ({fg_g^2, bg_g^2} per pixel)

// ---------------------------------------------------------------------------
// Kernel 1: column pass, bitmask edition. One wave (64 threads) per
// (image, 64-column group). The mask is packed via __ballot into one u64 per
// row (LDS, 2 KB); both serial scans then run on LDS/registers only — no
// global memory in the loop (round-2 counters: VALUBusy 0.9%, latency-bound
// on in-loop global load/store). d_up lives in LDS as u16 (2 lanes/bank =
// conflict-free). Distance from pixel i to the nearest opposite-class pixel
// in the column: track last/next index of BOTH classes, select the opposite
// one (matches the reference's inclusive cummax exactly). Sentinel: "none"
// init is +-30000, so a combined d >= 1000 means no opposite pixel in the
// column -> BIG (= reference's clamp), else d <= 255 exact.
// ---------------------------------------------------------------------------
__global__ __launch_bounds__(64) void col_pass_bits(
    const float* __restrict__ pred, const float* __restrict__ targ,
    float2* __restrict__ g2, int* __restrict__ flags) {
  const int img = blockIdx.x >> 2;                 // 0..15
  const int lane = threadIdx.x;                    // 0..63
  const int col = ((blockIdx.x & 3) << 6) + lane;  // 0..255
  const float* __restrict__ src =
      (img < 8) ? pred + img * NPIX : targ + (img - 8) * NPIX;
  float2* __restrict__ g = g2 + img * NPIX;

  __shared__ unsigned long long words[H];   // row bitmasks (this col group)
  __shared__ unsigned short dup[H][64];     // d_up per pixel

  // stage: coalesced float loads -> ballot -> one u64 per row
  unsigned long long anyw = 0;
#pragma unroll 8
  for (int i = 0; i < H; ++i) {
    const float v = src[i * W + col];
    const unsigned long long w = __ballot(v > 0.5f);
    if (lane == 0) words[i] = w;
    anyw |= w;
  }
  __syncthreads();
  if (lane == 0 && anyw) atomicOr(&flags[img], 1);

  // down scan: distance to nearest opposite-class pixel above (inclusive)
  int lastFg = -30000, lastBg = -30000;
#pragma unroll 4
  for (int i = 0; i < H; ++i) {
    const int bit = (int)((words[i] >> lane) & 1ull);
    lastFg = bit ? i : lastFg;
    lastBg = bit ? lastBg : i;
    const int lastOpp = bit ? lastBg : lastFg;
    dup[i][lane] = (unsigned short)(i - lastOpp);
  }
  __syncthreads();

  // up scan: combine, map sentinel to BIG, square, write selected pair
  int nextFg = 30000, nextBg = 30000;
#pragma unroll 4
  for (int i = H - 1; i >= 0; --i) {
    const int bit = (int)((words[i] >> lane) & 1ull);
    nextFg = bit ? i : nextFg;
    nextBg = bit ? nextBg : i;
    const int nextOpp = bit ? nextBg : nextFg;
    const int d = min((int)dup[i][lane], nextOpp - i);
    const float fd = (d >= 1000) ? BIG : (float)d;
    const float s = fd * fd;
    g[i * W + col] = bit ? make_float2(s, 0.0f) : make_float2(0.0f, s);
  }
}

// ---------------------------------------------------------------------------
// Kernel 2: row pass + loss, b128 edition. One block per (batch, row).
// Round-2 counters implied this kernel was LDS-ISSUE-bound (~2 ds_read_b32
// per k per thread ~= 40 us/CU). Fix: four separate 16B-aligned class rows
// in LDS; each thread selects its (loop-invariant) class pointer and reads
// float4 -> one ds_read_b128 per 4 k's per image (4x fewer LDS issues).
// Reads are wave-broadcast (<=2 distinct addresses/wave): conflict-free.
// fmaf(d,d,g) is exact here (integers < 2^24, or the 1e20 sentinel which
// absorbs the offset in fp32 exactly as the reference does).
// ---------------------------------------------------------------------------
__global__ __launch_bounds__(256) void row_pass(
    const float* __restrict__ pred, const float* __restrict__ targ,
    const float2* __restrict__ g2, const int* __restrict__ flags,
    double* __restrict__ partial) {
  const int b = blockIdx.x >> 8;       // batch 0..7
  const int i = blockIdx.x & (H - 1);  // row
  const int j = threadIdx.x;           // column

  __shared__ __align__(16) float gPF[W], gPB[W], gTF[W], gTB[W];
  {
    const float2 gp = g2[b * NPIX + i * W + j];
    const float2 gt = g2[(8 + b) * NPIX + i * W + j];
    gPF[j] = gp.x; gPB[j] = gp.y;   // 2 lanes/bank stride-1 writes: free
    gTF[j] = gt.x; gTB[j] = gt.y;
  }
  const int pix = b * NPIX + i * W + j;
  const float p = pred[pix];
  const float t = targ[pix];
  __syncthreads();

  // fg pixel -> edt(fg)^2 row; bg pixel -> edt(bg)^2 row (disjoint support)
  const float4* __restrict__ baseP = (const float4*)(p > 0.5f ? gPF : gPB);
  const float4* __restrict__ baseT = (const float4*)(t > 0.5f ? gTF : gTB);

  float dP = 3.0e38f, dT = 3.0e38f;
  float d0 = (float)j;  // j - k for the first element of the current quad
#pragma unroll 4
  for (int k4 = 0; k4 < W / 4; ++k4) {
    const float4 gp = baseP[k4];
    const float4 gt = baseT[k4];
    const float d1 = d0 - 1.0f, d2 = d0 - 2.0f, d3 = d0 - 3.0f;
    dP = fminf(dP, fmaf(d0, d0, gp.x));
    dP = fminf(dP, fmaf(d1, d1, gp.y));
    dP = fminf(dP, fmaf(d2, d2, gp.z));
    dP = fminf(dP, fmaf(d3, d3, gp.w));
    dT = fminf(dT, fmaf(d0, d0, gt.x));
    dT = fminf(dT, fmaf(d1, d1, gt.y));
    dT = fminf(dT, fmaf(d2, d2, gt.z));
    dT = fminf(dT, fmaf(d3, d3, gt.w));
    d0 -= 4.0f;
  }

  const float fP = flags[b] ? 1.0f : 0.0f;      // zero field if no fg (ref)
  const float fT = flags[8 + b] ? 1.0f : 0.0f;
  const float pe = (p - t) * (p - t);
  double c = (double)(pe * (dP * fP + dT * fT));

  // wave reduce then cross-wave via LDS; plain store (no atomics)
  for (int off = 32; off > 0; off >>= 1) c += __shfl_down(c, off);
  __shared__ double wsum[4];
  if ((j & 63) == 0) wsum[j >> 6] = c;
  __syncthreads();
  if (j == 0) partial[blockIdx.x] = wsum[0] + wsum[1] + wsum[2] + wsum[3];
}

// ---------------------------------------------------------------------------
// Kernel 3: reduce 2048 partials, scale, write fp32 result.
// ---------------------------------------------------------------------------
__global__ __launch_bounds__(256) void finalize(
    const double* __restrict__ partial, float* __restrict__ out) {
  double s = 0.0;
#pragma unroll
  for (int k = 0; k < 8; ++k) s += partial[threadIdx.x + (k << 8)];
  for (int off = 32; off > 0; off >>= 1) s += __shfl_down(s, off);
  __shared__ double ws[4];
  if ((threadIdx.x & 63) == 0) ws[threadIdx.x >> 6] = s;
  __syncthreads();
  if (threadIdx.x == 0)
    out[0] = (float)((ws[0] + ws[1] + ws[2] + ws[3]) *
                     (1.0 / (8.0 * (double)NPIX)));
}

extern "C" void kernel_launch(void* const* d_in, const int* in_sizes, int n_in,
                              void* d_out, int out_size, void* d_ws,
                              size_t ws_size, hipStream_t stream) {
  const float* pred = (const float*)d_in[0];
  const float* targ = (const float*)d_in[1];
  double* partial = (double*)d_ws;
  int* flags = (int*)((char*)d_ws + 16384);
  float2* g2 = (float2*)((char*)d_ws + 32768);

  hipMemsetAsync(flags, 0, 64, stream);  // zero fg.any() flags only
  col_pass_bits<<<64, 64, 0, stream>>>(pred, targ, g2, flags);
  row_pass<<<8 * H, 256, 0, stream>>>(pred, targ, g2, flags, partial);
  finalize<<<1, 256, 0, stream>>>(partial, (float*)d_out);
}

// Round 8
// 158.021 us; speedup vs baseline: 1.0716x; 1.0716x over previous
//
#include <hip/hip_runtime.h>

#define BIG 1e10f
#define H 256
#define W 256
#define NPIX (H * W)
// images: 0..7 = pred batch, 8..15 = target batch
// ws layout:
//   [0, 16384)            double partial[2048]   (one per row_pass block)
//   [16384, 16448)        int flags[16]          (fg.any() per image)
//   [32768, 32768+8MB)    float2 g2[16][H][W]    ({fg_g^2, bg_g^2} per pixel)

// ---------------------------------------------------------------------------
// Kernel 1: column pass, register edition. Round-7 post-mortem: the LDS
// version ran at 343 cy/iteration — one serialized memory round-trip per
// scan step, fully exposed at 1 wave/CU. Fix: each lane packs its column's
// 256 mask bits into FOUR u64 REGISTERS during a bulk unroll-32 coalesced
// load phase (independent loads -> 32 in flight); both scans are then pure
// register/VALU tracker loops (~12 ops/iter, no memory on the dependence
// chain). Down pass stores its partial {fg^2,bg^2} pair (fire-and-forget);
// up pass re-loads those per-lane addresses (independent -> prefetchable),
// fmins componentwise, stores final. min/clamp/square commute (monotone on
// nonneg ints), so output is bit-identical to the round-2/7 kernels:
// valid distances <= 255 exact; no-opposite sentinel (tracker at +-30000,
// d >= 1000) -> BIG, squared in fp32 exactly like the reference.
// ---------------------------------------------------------------------------
__global__ __launch_bounds__(64) void col_pass_reg(
    const float* __restrict__ pred, const float* __restrict__ targ,
    float2* __restrict__ g2, int* __restrict__ flags) {
  const int img = blockIdx.x >> 2;                 // 0..15
  const int lane = threadIdx.x;                    // 0..63
  const int col = ((blockIdx.x & 3) << 6) + lane;  // 0..255
  const float* __restrict__ src =
      (img < 8) ? pred + img * NPIX : targ + (img - 8) * NPIX;
  float2* __restrict__ g = g2 + img * NPIX;

  // ---- stage: pack column bits into m0..m3 (bit r of mq = row 64q+r) ----
  unsigned long long m0 = 0, m1 = 0, m2 = 0, m3 = 0;
#define STAGE(MW, BASE)                                         \
  _Pragma("unroll 32") for (int r = 0; r < 64; ++r) {           \
    const float v = src[(BASE + r) * W + col];                  \
    MW |= ((unsigned long long)(v > 0.5f)) << r;                \
  }
  STAGE(m0, 0) STAGE(m1, 64) STAGE(m2, 128) STAGE(m3, 192)
#undef STAGE

  if (__any((m0 | m1 | m2 | m3) != 0ull) && lane == 0)
    atomicOr(&flags[img], 1);  // fg.any() for this image

  // ---- down pass: distance to nearest opposite-class bit above ----
  // last0/last1 = last index with bit 0 / bit 1 (inclusive; own class at i
  // updates its own tracker, the OPPOSITE tracker is what we subtract).
  int last0 = -30000, last1 = -30000;
#define DOWN(MW, BASE)                                          \
  _Pragma("unroll 16") for (int r = 0; r < 64; ++r) {           \
    const int i = BASE + r;                                     \
    const int bit = (int)((MW >> r) & 1ull);                    \
    last0 = bit ? last0 : i;                                    \
    last1 = bit ? i : last1;                                    \
    const int dA = i - (bit ? last0 : last1);                   \
    const float fd = (dA >= 1000) ? BIG : (float)dA;            \
    const float s = fd * fd;                                    \
    g[i * W + col] = bit ? make_float2(s, 0.0f)                 \
                         : make_float2(0.0f, s);                \
  }
  DOWN(m0, 0) DOWN(m1, 64) DOWN(m2, 128) DOWN(m3, 192)
#undef DOWN

  // ---- up pass: combine with distance below, fmin, final store ----
  int next0 = 30000, next1 = 30000;
#define UP(MW, BASE)                                            \
  _Pragma("unroll 16") for (int r = 63; r >= 0; --r) {          \
    const int i = BASE + r;                                     \
    const int bit = (int)((MW >> r) & 1ull);                    \
    next0 = bit ? next0 : i;                                    \
    next1 = bit ? i : next1;                                    \
    const int dB = (bit ? next0 : next1) - i;                   \
    const float fd = (dB >= 1000) ? BIG : (float)dB;            \
    const float s = fd * fd;                                    \
    const float2 pa = g[i * W + col];                           \
    const float2 pb = bit ? make_float2(s, 0.0f)                \
                          : make_float2(0.0f, s);               \
    g[i * W + col] =                                            \
        make_float2(fminf(pa.x, pb.x), fminf(pa.y, pb.y));      \
  }
  UP(m3, 192) UP(m2, 128) UP(m1, 64) UP(m0, 0)
#undef UP
}

// ---------------------------------------------------------------------------
// Kernel 2: row pass + loss, b128 edition (UNCHANGED — attribution).
// One block per (batch, row). Disjoint-support selection: each thread scans
// ONE envelope per image (class pointer selected before the loop). float4
// LDS reads -> ds_read_b128, wave-broadcast, conflict-free. fmaf exact
// (integers < 2^24 or the 1e20 sentinel absorbing offsets as in reference).
// ---------------------------------------------------------------------------
__global__ __launch_bounds__(256) void row_pass(
    const float* __restrict__ pred, const float* __restrict__ targ,
    const float2* __restrict__ g2, const int* __restrict__ flags,
    double* __restrict__ partial) {
  const int b = blockIdx.x >> 8;       // batch 0..7
  const int i = blockIdx.x & (H - 1);  // row
  const int j = threadIdx.x;           // column

  __shared__ __align__(16) float gPF[W], gPB[W], gTF[W], gTB[W];
  {
    const float2 gp = g2[b * NPIX + i * W + j];
    const float2 gt = g2[(8 + b) * NPIX + i * W + j];
    gPF[j] = gp.x; gPB[j] = gp.y;
    gTF[j] = gt.x; gTB[j] = gt.y;
  }
  const int pix = b * NPIX + i * W + j;
  const float p = pred[pix];
  const float t = targ[pix];
  __syncthreads();

  const float4* __restrict__ baseP = (const float4*)(p > 0.5f ? gPF : gPB);
  const float4* __restrict__ baseT = (const float4*)(t > 0.5f ? gTF : gTB);

  float dP = 3.0e38f, dT = 3.0e38f;
  float d0 = (float)j;
#pragma unroll 4
  for (int k4 = 0; k4 < W / 4; ++k4) {
    const float4 gp = baseP[k4];
    const float4 gt = baseT[k4];
    const float d1 = d0 - 1.0f, d2 = d0 - 2.0f, d3 = d0 - 3.0f;
    dP = fminf(dP, fmaf(d0, d0, gp.x));
    dP = fminf(dP, fmaf(d1, d1, gp.y));
    dP = fminf(dP, fmaf(d2, d2, gp.z));
    dP = fminf(dP, fmaf(d3, d3, gp.w));
    dT = fminf(dT, fmaf(d0, d0, gt.x));
    dT = fminf(dT, fmaf(d1, d1, gt.y));
    dT = fminf(dT, fmaf(d2, d2, gt.z));
    dT = fminf(dT, fmaf(d3, d3, gt.w));
    d0 -= 4.0f;
  }

  const float fP = flags[b] ? 1.0f : 0.0f;
  const float fT = flags[8 + b] ? 1.0f : 0.0f;
  const float pe = (p - t) * (p - t);
  double c = (double)(pe * (dP * fP + dT * fT));

  for (int off = 32; off > 0; off >>= 1) c += __shfl_down(c, off);
  __shared__ double wsum[4];
  if ((j & 63) == 0) wsum[j >> 6] = c;
  __syncthreads();
  if (j == 0) partial[blockIdx.x] = wsum[0] + wsum[1] + wsum[2] + wsum[3];
}

// ---------------------------------------------------------------------------
// Kernel 3: reduce 2048 partials, scale, write fp32 result.
// ---------------------------------------------------------------------------
__global__ __launch_bounds__(256) void finalize(
    const double* __restrict__ partial, float* __restrict__ out) {
  double s = 0.0;
#pragma unroll
  for (int k = 0; k < 8; ++k) s += partial[threadIdx.x + (k << 8)];
  for (int off = 32; off > 0; off >>= 1) s += __shfl_down(s, off);
  __shared__ double ws[4];
  if ((threadIdx.x & 63) == 0) ws[threadIdx.x >> 6] = s;
  __syncthreads();
  if (threadIdx.x == 0)
    out[0] = (float)((ws[0] + ws[1] + ws[2] + ws[3]) *
                     (1.0 / (8.0 * (double)NPIX)));
}

extern "C" void kernel_launch(void* const* d_in, const int* in_sizes, int n_in,
                              void* d_out, int out_size, void* d_ws,
                              size_t ws_size, hipStream_t stream) {
  const float* pred = (const float*)d_in[0];
  const float* targ = (const float*)d_in[1];
  double* partial = (double*)d_ws;
  int* flags = (int*)((char*)d_ws + 16384);
  float2* g2 = (float2*)((char*)d_ws + 32768);

  hipMemsetAsync(flags, 0, 64, stream);  // zero fg.any() flags only
  col_pass_reg<<<64, 64, 0, stream>>>(pred, targ, g2, flags);
  row_pass<<<8 * H, 256, 0, stream>>>(pred, targ, g2, flags, partial);
  finalize<<<1, 256, 0, stream>>>(partial, (float*)d_out);
}

// Round 10
// 79.341 us; speedup vs baseline: 2.1342x; 1.9917x over previous
//
#include <hip/hip_runtime.h>

#define BIG2 1e20f  // BIG^2 (1e10^2), matches reference clamp-then-square in fp32
#define H 256
#define W 256
#define NPIX (H * W)
typedef unsigned long long u64;
// images: 0..7 = pred batch, 8..15 = target batch
// ws layout:
//   [0, 16384)        double partial[2048]     (one per fused block)
//   [16384, 16448)    int flags[16]            (fg.any() per image)
//   [32768, 163840)   u64 rowmask[16][256][4]  (bit c of word w = pixel(row, 64w+c) > 0.5)

// ---------------------------------------------------------------------------
// Kernel A: build row bitmasks. 128 blocks (16 img x 8 rowgroups) x 64 thr.
// Per row: 4 coalesced 256B loads + 4 ballots -> 32B of mask. Loads are all
// independent -> pipelined. Replaces the serial column scan entirely
// (rounds 2/7/8: every scan-structured col kernel pinned at 90-130us,
// latency-bound at 1 wave/CU).
// ---------------------------------------------------------------------------
__global__ __launch_bounds__(64) void mask_build(
    const float* __restrict__ pred, const float* __restrict__ targ,
    u64* __restrict__ rowmask, int* __restrict__ flags) {
  const int img = blockIdx.x >> 3;  // 0..15
  const int rg = blockIdx.x & 7;    // 0..7 (32 rows each)
  const int lane = threadIdx.x;
  const float* __restrict__ src =
      (img < 8) ? pred + img * NPIX : targ + (img - 8) * NPIX;
  u64* __restrict__ rm = rowmask + img * 1024;

  u64 anyw = 0;
#pragma unroll 8
  for (int rr = 0; rr < 32; ++rr) {
    const int r = (rg << 5) + rr;
    const u64 w0 = __ballot(src[r * W + lane] > 0.5f);
    const u64 w1 = __ballot(src[r * W + 64 + lane] > 0.5f);
    const u64 w2 = __ballot(src[r * W + 128 + lane] > 0.5f);
    const u64 w3 = __ballot(src[r * W + 192 + lane] > 0.5f);
    anyw |= (w0 | w1 | w2 | w3);
    if (lane == 0) {
      ulonglong2 a; a.x = w0; a.y = w1;
      ulonglong2 b; b.x = w2; b.y = w3;
      ulonglong2* pp = (ulonglong2*)(rm + r * 4);
      pp[0] = a;
      pp[1] = b;
    }
  }
  if (lane == 0 && anyw) atomicOr(&flags[img], 1);
}

// ---------------------------------------------------------------------------
// Kernel B: fused vertical-EDT + row-EDT + loss. One block per (batch, row):
// 2048 blocks x 256 thr = 32 waves/CU (vs 0.6% occupancy before).
// Vertical distance: probe mask rows i+-d (wave-uniform broadcast LDS reads)
// until the opposite bit appears — exact, ~6 wave-iters on random data,
// bounded by 255. Row scan: pruned at d^2 >= best (exact: g^2>=0, init best
// = dv^2 = the k=j candidate). All quantities integer-exact in fp32 or the
// BIG2 sentinel — bit-identical to the validated rounds' math.
// ---------------------------------------------------------------------------
__global__ __launch_bounds__(256) void fused_edt_loss(
    const float* __restrict__ pred, const float* __restrict__ targ,
    const u64* __restrict__ rowmask, const int* __restrict__ flags,
    double* __restrict__ partial) {
  const int b = blockIdx.x >> 8;       // batch 0..7
  const int i = blockIdx.x & (H - 1);  // row
  const int j = threadIdx.x;           // column

  __shared__ u64 mP[H * 4], mT[H * 4];  // [row][word], 8 KB each
  __shared__ __align__(16) float gPF[W], gPB[W], gTF[W], gTB[W];
  __shared__ double wsum[4];

  {  // stage both mask sets: coalesced 16B loads, L2-resident source
    const ulonglong2* gp = (const ulonglong2*)(rowmask + b * 1024);
    const ulonglong2* gt = (const ulonglong2*)(rowmask + (8 + b) * 1024);
    ulonglong2* sp = (ulonglong2*)mP;
    ulonglong2* st = (ulonglong2*)mT;
    sp[j] = gp[j]; sp[j + 256] = gp[j + 256];
    st[j] = gt[j]; st[j + 256] = gt[j + 256];
  }
  const int pix = b * NPIX + i * W + j;
  const float p = pred[pix];
  const float t = targ[pix];
  __syncthreads();

  const int wrd = j >> 6;  // wave-uniform word index
  const int sh = j & 63;
  const int clP = (int)((mP[i * 4 + wrd] >> sh) & 1ull);
  const int clT = (int)((mT[i * 4 + wrd] >> sh) & 1ull);

  // ---- vertical walk: nearest opposite-class row in this column ----
  int dP = 0, dT = 0;  // 0 = not found yet
  const int dmax = (i > (H - 1 - i)) ? i : (H - 1 - i);
  for (int d = 1; d <= dmax; ++d) {
    if (__all((dP != 0) & (dT != 0))) break;
    const int iu = i - d, id = i + d;
    if (dP == 0) {
      int f = 0;
      if (iu >= 0) f |= (int)((mP[iu * 4 + wrd] >> sh) & 1ull) ^ clP;
      if (id < H) f |= (int)((mP[id * 4 + wrd] >> sh) & 1ull) ^ clP;
      if (f) dP = d;
    }
    if (dT == 0) {
      int f = 0;
      if (iu >= 0) f |= (int)((mT[iu * 4 + wrd] >> sh) & 1ull) ^ clT;
      if (id < H) f |= (int)((mT[id * 4 + wrd] >> sh) & 1ull) ^ clT;
      if (f) dT = d;
    }
  }
  const float dv2P = dP ? (float)(dP * dP) : BIG2;
  const float dv2T = dT ? (float)(dT * dT) : BIG2;

  // envelopes: g_fg[k] = (k is fg) ? dv2 : 0 ; g_bg[k] = (k is fg) ? 0 : dv2
  gPF[j] = clP ? dv2P : 0.0f;
  gPB[j] = clP ? 0.0f : dv2P;
  gTF[j] = clT ? dv2T : 0.0f;
  gTB[j] = clT ? 0.0f : dv2T;
  __syncthreads();

  // ---- pruned row scan (disjoint support: query own-class envelope) ----
  const float* __restrict__ baseP = clP ? gPF : gPB;
  const float* __restrict__ baseT = clT ? gTF : gTB;
  float bestP = dv2P, bestT = dv2T;  // k=j candidate
  for (int d = 1; d < W; ++d) {
    const float dd = (float)(d * d);
    if (__all((dd >= bestP) & (dd >= bestT))) break;
    const int kL = j - d, kR = j + d;
    const int kLc = kL < 0 ? 0 : kL;         // clamped LDS index
    const int kRc = kR > W - 1 ? W - 1 : kR;
    const float cP = fminf(kL >= 0 ? baseP[kLc] : BIG2,
                           kR < W ? baseP[kRc] : BIG2);
    const float cT = fminf(kL >= 0 ? baseT[kLc] : BIG2,
                           kR < W ? baseT[kRc] : BIG2);
    bestP = fminf(bestP, cP + dd);
    bestT = fminf(bestT, cT + dd);
  }

  // ---- loss ----
  const float fP = flags[b] ? 1.0f : 0.0f;      // zero field if no fg (ref)
  const float fT = flags[8 + b] ? 1.0f : 0.0f;
  const float pe = (p - t) * (p - t);
  double c = (double)(pe * (bestP * fP + bestT * fT));

  for (int off = 32; off > 0; off >>= 1) c += __shfl_down(c, off);
  if ((j & 63) == 0) wsum[j >> 6] = c;
  __syncthreads();
  if (j == 0) partial[blockIdx.x] = wsum[0] + wsum[1] + wsum[2] + wsum[3];
}

// ---------------------------------------------------------------------------
// Kernel C: reduce 2048 partials, scale, write fp32 result.
// ---------------------------------------------------------------------------
__global__ __launch_bounds__(256) void finalize(
    const double* __restrict__ partial, float* __restrict__ out) {
  double s = 0.0;
#pragma unroll
  for (int k = 0; k < 8; ++k) s += partial[threadIdx.x + (k << 8)];
  for (int off = 32; off > 0; off >>= 1) s += __shfl_down(s, off);
  __shared__ double ws[4];
  if ((threadIdx.x & 63) == 0) ws[threadIdx.x >> 6] = s;
  __syncthreads();
  if (threadIdx.x == 0)
    out[0] = (float)((ws[0] + ws[1] + ws[2] + ws[3]) *
                     (1.0 / (8.0 * (double)NPIX)));
}

extern "C" void kernel_launch(void* const* d_in, const int* in_sizes, int n_in,
                              void* d_out, int out_size, void* d_ws,
                              size_t ws_size, hipStream_t stream) {
  const float* pred = (const float*)d_in[0];
  const float* targ = (const float*)d_in[1];
  double* partial = (double*)d_ws;
  int* flags = (int*)((char*)d_ws + 16384);
  u64* rowmask = (u64*)((char*)d_ws + 32768);

  hipMemsetAsync(flags, 0, 64, stream);  // zero fg.any() flags only
  mask_build<<<128, 64, 0, stream>>>(pred, targ, rowmask, flags);
  fused_edt_loss<<<8 * H, 256, 0, stream>>>(pred, targ, rowmask, flags,
                                            partial);
  finalize<<<1, 256, 0, stream>>>(partial, (float*)d_out);
}